// Round 4
// baseline (144.107 us; speedup 1.0000x reference)
//
#include <hip/hip_runtime.h>
#include <math.h>

#define NCTRL 9
#define DIM 12           // NCTRL + 3
#define NCOLS (DIM + 2)  // 12 matrix cols + 2 RHS (QX, QY)
#define OUT_H 512
#define OUT_W 512
#define BATCH 32
#define PIX_PER_THREAD 8

// Native clang vector type — required by __builtin_nontemporal_store
// (HIP's float4 is a class and is rejected by the builtin).
typedef float nfloat4 __attribute__((ext_vector_type(4)));

// ---------------------------------------------------------------------------
// Kernel 1: per-batch TPS coefficient solve.
// L v = [Q; 0]  with  L = [[K, P], [P^T, 0]],  K_ij = d2*log(d2), d2==0 -> 0.
// One block (one wave, 64 threads) per batch. Gauss-Jordan with partial
// pivoting in fp64 LDS (K diagonal is zero -> pivoting required).
// Output coef layout per batch: WX[9], WY[9], AX[3], AY[3]  (24 floats).
// ---------------------------------------------------------------------------
__global__ __launch_bounds__(64) void tps_solve_kernel(
    const float* __restrict__ theta, float* __restrict__ coef) {
    const int b = blockIdx.x;
    const int lane = threadIdx.x;  // 0..63, single wave
    const float* th = theta + b * 36;  // QX[0:9] QY[9:18] PX[18:27] PY[27:36]

    __shared__ double M[DIM][NCOLS + 1];  // +1 pad
    __shared__ double fshare[DIM];

    // Fill augmented matrix (12 x 14)
    for (int e = lane; e < DIM * NCOLS; e += 64) {
        const int r = e / NCOLS;
        const int c = e % NCOLS;
        double v;
        if (c < DIM) {
            if (r < NCTRL && c < NCTRL) {
                const double dx = (double)th[18 + r] - (double)th[18 + c];
                const double dy = (double)th[27 + r] - (double)th[27 + c];
                const double d2 = dx * dx + dy * dy;
                v = (d2 == 0.0) ? 0.0 : d2 * log(d2);
            } else if (r < NCTRL) {              // P block, c in 9..11
                v = (c == 9) ? 1.0 : (c == 10 ? (double)th[18 + r] : (double)th[27 + r]);
            } else if (c < NCTRL) {              // P^T block, r in 9..11
                v = (r == 9) ? 1.0 : (r == 10 ? (double)th[18 + c] : (double)th[27 + c]);
            } else {
                v = 0.0;                         // Z block
            }
        } else if (c == DIM) {                   // RHS x: [QX; 0]
            v = (r < NCTRL) ? (double)th[r] : 0.0;
        } else {                                 // RHS y: [QY; 0]
            v = (r < NCTRL) ? (double)th[9 + r] : 0.0;
        }
        M[r][c] = v;
    }
    __syncthreads();

    for (int k = 0; k < DIM; ++k) {
        // Partial pivot: argmax over |M[r][k]|, r in [k, 12). Candidates live
        // only in lanes 0..11, so a 16-lane butterfly (4 stages) suffices.
        double mv = (lane >= k && lane < DIM) ? fabs(M[lane][k]) : -1.0;
        int mi = lane;
        #pragma unroll
        for (int off = 8; off > 0; off >>= 1) {
            const double ov = __shfl_xor(mv, off);
            const int oi = __shfl_xor(mi, off);
            if (ov > mv) { mv = ov; mi = oi; }
        }
        mi = __shfl(mi, 0);  // wave-uniform pivot row (lane 0 covers 0..15)
        if (mi != k && lane < NCOLS) {
            const double tmp = M[k][lane];
            M[k][lane] = M[mi][lane];
            M[mi][lane] = tmp;
        }
        __syncthreads();

        const double piv = M[k][k];
        if (lane < DIM && lane != k) fshare[lane] = M[lane][k] / piv;
        __syncthreads();

        // Eliminate column k from all other rows (Gauss-Jordan)
        for (int e = lane; e < DIM * NCOLS; e += 64) {
            const int r = e / NCOLS;
            const int c = e % NCOLS;
            if (r != k && c >= k) M[r][c] -= fshare[r] * M[k][c];
        }
        __syncthreads();
    }

    if (lane < DIM) {
        const double x = M[lane][DIM] / M[lane][lane];
        const double y = M[lane][DIM + 1] / M[lane][lane];
        float* cb = coef + b * 24;
        if (lane < NCTRL) {
            cb[lane] = (float)x;          // WX
            cb[9 + lane] = (float)y;      // WY
        } else {
            cb[18 + (lane - 9)] = (float)x;  // AX
            cb[21 + (lane - 9)] = (float)y;  // AY
        }
    }
}

// ---------------------------------------------------------------------------
// Kernel 2: grid evaluation. 8 adjacent pixels per thread, 4x 16B
// nontemporal stores (streaming output, no reuse -> skip L2).
// grid = (H*W/8/256, BATCH) = (128, 32), block = 256.
// ---------------------------------------------------------------------------
__global__ __launch_bounds__(256) void tps_grid_kernel(
    const float* __restrict__ theta, const float* __restrict__ coef,
    float* __restrict__ out) {
    const int b = blockIdx.y;
    const float* th = theta + b * 36;
    const float* cf = coef + b * 24;

    // Uniform (scalar) loads of per-batch params
    float PX[NCTRL], PY[NCTRL], WX[NCTRL], WY[NCTRL];
    #pragma unroll
    for (int n = 0; n < NCTRL; ++n) {
        PX[n] = th[18 + n];
        PY[n] = th[27 + n];
        WX[n] = cf[n];
        WY[n] = cf[9 + n];
    }
    const float AX0 = cf[18], AX1 = cf[19], AX2 = cf[20];
    const float AY0 = cf[21], AY1 = cf[22], AY2 = cf[23];

    const int p = blockIdx.x * 256 + threadIdx.x;  // pixel-oct index
    const int pix = p * PIX_PER_THREAD;            // first pixel (w % 8 == 0)
    const int w = pix & (OUT_W - 1);
    const int h = pix >> 9;

    const float step = 2.0f / 511.0f;
    const float gx0 = -1.0f + step * (float)w;
    const float gy = -1.0f + step * (float)h;

    float xp[PIX_PER_THREAD], yp[PIX_PER_THREAD];
    #pragma unroll
    for (int i = 0; i < PIX_PER_THREAD; ++i) {
        const float gx = gx0 + step * (float)i;
        xp[i] = AX0 + AX1 * gx + AX2 * gy;
        yp[i] = AY0 + AY1 * gx + AY2 * gy;
    }

    #pragma unroll
    for (int n = 0; n < NCTRL; ++n) {
        const float dy = gy - PY[n];
        const float dy2 = dy * dy;
        float dx = gx0 - PX[n];
        #pragma unroll
        for (int i = 0; i < PIX_PER_THREAD; ++i) {
            const float r2 = __builtin_fmaf(dx, dx, dy2);
            // r2==0 -> u = 0 * log(1e-30) = -0.f == ref's 0 (d2->1, log1=0)
            const float u = r2 * __logf(fmaxf(r2, 1e-30f));
            xp[i] = __builtin_fmaf(u, WX[n], xp[i]);
            yp[i] = __builtin_fmaf(u, WY[n], yp[i]);
            dx += step;
        }
    }

    const size_t off = ((size_t)b * (OUT_H * OUT_W) + (size_t)pix) * 2;
    #pragma unroll
    for (int q = 0; q < PIX_PER_THREAD / 2; ++q) {
        nfloat4 o = {xp[2 * q], yp[2 * q], xp[2 * q + 1], yp[2 * q + 1]};
        __builtin_nontemporal_store(o, (nfloat4*)(out + off + 4 * q));
    }
}

extern "C" void kernel_launch(void* const* d_in, const int* in_sizes, int n_in,
                              void* d_out, int out_size, void* d_ws, size_t ws_size,
                              hipStream_t stream) {
    const float* theta = (const float*)d_in[0];
    float* out = (float*)d_out;
    float* coef = (float*)d_ws;  // 32 * 24 floats = 3 KiB

    tps_solve_kernel<<<dim3(BATCH), dim3(64), 0, stream>>>(theta, coef);

    const int octs_per_batch = (OUT_H * OUT_W) / PIX_PER_THREAD;  // 32768
    const int blocks_x = octs_per_batch / 256;                    // 128
    tps_grid_kernel<<<dim3(blocks_x, BATCH), dim3(256), 0, stream>>>(theta, coef, out);
}

// Round 5
// 110.135 us; speedup vs baseline: 1.3085x; 1.3085x over previous
//
#include <hip/hip_runtime.h>
#include <math.h>

#define NCTRL 9
#define DIM 12           // NCTRL + 3
#define NCOLS (DIM + 2)  // 12 matrix cols + 2 RHS (QX, QY)
#define OUT_H 512
#define OUT_W 512
#define BATCH 32

// Native clang vector type — required by __builtin_nontemporal_store
// (HIP's float4 is a class and is rejected by the builtin).
typedef float nfloat4 __attribute__((ext_vector_type(4)));

// ---------------------------------------------------------------------------
// Kernel 1: per-batch TPS coefficient solve.
// L v = [Q; 0]  with  L = [[K, P], [P^T, 0]],  K_ij = d2*log(d2), d2==0 -> 0.
// One block (one wave, 64 threads) per batch. Gauss-Jordan with partial
// pivoting in fp64 LDS (K diagonal is zero -> pivoting required).
// Output coef layout per batch: WX[9], WY[9], AX[3], AY[3]  (24 floats).
// ---------------------------------------------------------------------------
__global__ __launch_bounds__(64) void tps_solve_kernel(
    const float* __restrict__ theta, float* __restrict__ coef) {
    const int b = blockIdx.x;
    const int lane = threadIdx.x;  // 0..63, single wave
    const float* th = theta + b * 36;  // QX[0:9] QY[9:18] PX[18:27] PY[27:36]

    __shared__ double M[DIM][NCOLS + 1];  // +1 pad
    __shared__ double fshare[DIM];

    // Fill augmented matrix (12 x 14)
    for (int e = lane; e < DIM * NCOLS; e += 64) {
        const int r = e / NCOLS;
        const int c = e % NCOLS;
        double v;
        if (c < DIM) {
            if (r < NCTRL && c < NCTRL) {
                const double dx = (double)th[18 + r] - (double)th[18 + c];
                const double dy = (double)th[27 + r] - (double)th[27 + c];
                const double d2 = dx * dx + dy * dy;
                v = (d2 == 0.0) ? 0.0 : d2 * log(d2);
            } else if (r < NCTRL) {              // P block, c in 9..11
                v = (c == 9) ? 1.0 : (c == 10 ? (double)th[18 + r] : (double)th[27 + r]);
            } else if (c < NCTRL) {              // P^T block, r in 9..11
                v = (r == 9) ? 1.0 : (r == 10 ? (double)th[18 + c] : (double)th[27 + c]);
            } else {
                v = 0.0;                         // Z block
            }
        } else if (c == DIM) {                   // RHS x: [QX; 0]
            v = (r < NCTRL) ? (double)th[r] : 0.0;
        } else {                                 // RHS y: [QY; 0]
            v = (r < NCTRL) ? (double)th[9 + r] : 0.0;
        }
        M[r][c] = v;
    }
    __syncthreads();

    for (int k = 0; k < DIM; ++k) {
        // Partial pivot: argmax over |M[r][k]|, r in [k, 12). Candidates live
        // only in lanes 0..11, so a 16-lane butterfly (4 stages) suffices.
        double mv = (lane >= k && lane < DIM) ? fabs(M[lane][k]) : -1.0;
        int mi = lane;
        #pragma unroll
        for (int off = 8; off > 0; off >>= 1) {
            const double ov = __shfl_xor(mv, off);
            const int oi = __shfl_xor(mi, off);
            if (ov > mv) { mv = ov; mi = oi; }
        }
        mi = __shfl(mi, 0);  // wave-uniform pivot row (lane 0 covers 0..15)
        if (mi != k && lane < NCOLS) {
            const double tmp = M[k][lane];
            M[k][lane] = M[mi][lane];
            M[mi][lane] = tmp;
        }
        __syncthreads();

        const double piv = M[k][k];
        if (lane < DIM && lane != k) fshare[lane] = M[lane][k] / piv;
        __syncthreads();

        // Eliminate column k from all other rows (Gauss-Jordan)
        for (int e = lane; e < DIM * NCOLS; e += 64) {
            const int r = e / NCOLS;
            const int c = e % NCOLS;
            if (r != k && c >= k) M[r][c] -= fshare[r] * M[k][c];
        }
        __syncthreads();
    }

    if (lane < DIM) {
        const double x = M[lane][DIM] / M[lane][lane];
        const double y = M[lane][DIM + 1] / M[lane][lane];
        float* cb = coef + b * 24;
        if (lane < NCTRL) {
            cb[lane] = (float)x;          // WX
            cb[9 + lane] = (float)y;      // WY
        } else {
            cb[18 + (lane - 9)] = (float)x;  // AX
            cb[21 + (lane - 9)] = (float)y;  // AY
        }
    }
}

// ---------------------------------------------------------------------------
// Kernel 2: grid evaluation. 8 pixels per thread arranged as 2 cols x 4 ROWS:
// thread t covers cols (2t, 2t+1) of 4 consecutive rows. Each of the 4
// 16B nontemporal stores is lane-CONTIGUOUS (lane stride 16B -> wave writes
// 1KiB, block writes a full 4KiB row per instruction). Round-4 lesson: 8
// ADJACENT pixels/thread made lane stride 64B per store instruction ->
// partial-line nt writes -> WRITE_SIZE 2.3x amplification (152MB vs 67MB).
// grid = (H/4, BATCH) = (128, 32), block = 256.
// ---------------------------------------------------------------------------
__global__ __launch_bounds__(256) void tps_grid_kernel(
    const float* __restrict__ theta, const float* __restrict__ coef,
    float* __restrict__ out) {
    const int b = blockIdx.y;
    const float* th = theta + b * 36;
    const float* cf = coef + b * 24;

    // Uniform (scalar) loads of per-batch params
    float PX[NCTRL], PY[NCTRL], WX[NCTRL], WY[NCTRL];
    #pragma unroll
    for (int n = 0; n < NCTRL; ++n) {
        PX[n] = th[18 + n];
        PY[n] = th[27 + n];
        WX[n] = cf[n];
        WY[n] = cf[9 + n];
    }
    const float AX0 = cf[18], AX1 = cf[19], AX2 = cf[20];
    const float AY0 = cf[21], AY1 = cf[22], AY2 = cf[23];

    const int t = threadIdx.x;
    const int row0 = blockIdx.x * 4;       // first of 4 consecutive rows
    const int col0 = t * 2;                // this thread's column pair

    const float step = 2.0f / 511.0f;
    const float gx0 = -1.0f + step * (float)col0;
    const float gx1 = gx0 + step;
    const float gy0 = -1.0f + step * (float)row0;

    float xp[8], yp[8];                    // [row q][col i] at index q*2+i
    #pragma unroll
    for (int q = 0; q < 4; ++q) {
        const float gy = gy0 + step * (float)q;
        xp[q * 2 + 0] = AX0 + AX1 * gx0 + AX2 * gy;
        yp[q * 2 + 0] = AY0 + AY1 * gx0 + AY2 * gy;
        xp[q * 2 + 1] = AX0 + AX1 * gx1 + AX2 * gy;
        yp[q * 2 + 1] = AY0 + AY1 * gx1 + AY2 * gy;
    }

    #pragma unroll
    for (int n = 0; n < NCTRL; ++n) {
        const float dx0 = gx0 - PX[n];
        const float dx1 = dx0 + step;
        const float dx0sq = dx0 * dx0;
        const float dx1sq = dx1 * dx1;
        float dy = gy0 - PY[n];
        #pragma unroll
        for (int q = 0; q < 4; ++q) {
            const float r20 = __builtin_fmaf(dy, dy, dx0sq);
            const float r21 = __builtin_fmaf(dy, dy, dx1sq);
            // r2==0 -> u = 0 * log(1e-30) = -0.f == ref's 0 (d2->1, log1=0)
            const float u0 = r20 * __logf(fmaxf(r20, 1e-30f));
            const float u1 = r21 * __logf(fmaxf(r21, 1e-30f));
            xp[q * 2 + 0] = __builtin_fmaf(u0, WX[n], xp[q * 2 + 0]);
            yp[q * 2 + 0] = __builtin_fmaf(u0, WY[n], yp[q * 2 + 0]);
            xp[q * 2 + 1] = __builtin_fmaf(u1, WX[n], xp[q * 2 + 1]);
            yp[q * 2 + 1] = __builtin_fmaf(u1, WY[n], yp[q * 2 + 1]);
            dy += step;
        }
    }

    #pragma unroll
    for (int q = 0; q < 4; ++q) {
        const size_t off =
            (((size_t)b * OUT_H + (size_t)(row0 + q)) * OUT_W + (size_t)col0) * 2;
        nfloat4 o = {xp[q * 2], yp[q * 2], xp[q * 2 + 1], yp[q * 2 + 1]};
        __builtin_nontemporal_store(o, (nfloat4*)(out + off));
    }
}

extern "C" void kernel_launch(void* const* d_in, const int* in_sizes, int n_in,
                              void* d_out, int out_size, void* d_ws, size_t ws_size,
                              hipStream_t stream) {
    const float* theta = (const float*)d_in[0];
    float* out = (float*)d_out;
    float* coef = (float*)d_ws;  // 32 * 24 floats = 3 KiB

    tps_solve_kernel<<<dim3(BATCH), dim3(64), 0, stream>>>(theta, coef);

    tps_grid_kernel<<<dim3(OUT_H / 4, BATCH), dim3(256), 0, stream>>>(theta, coef, out);
}